// Round 1
// baseline (181.820 us; speedup 1.0000x reference)
//
#include <hip/hip_runtime.h>
#include <hip/hip_bf16.h>

// Problem constants
#define BATCH 8
#define TLEN 2048
#define CDIM 1024
#define HDIM 64
#define BT (BATCH * TLEN)   // 16384

typedef __attribute__((ext_vector_type(8))) short short8;
typedef __attribute__((ext_vector_type(4))) float f32x4;

#define LPAD 88   // LDS row stride in shorts: 176B, 16B-aligned, conflict-friendly

__device__ inline short f2bf(float f) {
    unsigned u = __builtin_bit_cast(unsigned, f);
    unsigned r = (u + 0x7fffu + ((u >> 16) & 1u)) >> 16;
    return (short)r;
}

// ---------------------------------------------------------------------------
// Kernel 0: transpose + bf16-cast weights. Wt[3][64 n][1024 k] = W[k][n].
// Folds the attention scale 1/sqrt(H)=0.125 into Wq.
// ---------------------------------------------------------------------------
__global__ __launch_bounds__(256) void wt_kernel(
        const float* __restrict__ Wq, const float* __restrict__ Wk,
        const float* __restrict__ Wv, short* __restrict__ Wt) {
    const int kc = blockIdx.x * 64;   // k chunk
    const int wi = blockIdx.y;        // which weight
    const float* W = (wi == 0) ? Wq : ((wi == 1) ? Wk : Wv);
    const float scale = (wi == 0) ? 0.125f : 1.0f;
    __shared__ short tile[64][65];
    const int t = threadIdx.x;
    #pragma unroll
    for (int i = 0; i < 16; ++i) {
        int flat = i * 256 + t;            // coalesced over n
        int kk = flat >> 6, n = flat & 63;
        tile[kk][n] = f2bf(W[(size_t)(kc + kk) * HDIM + n] * scale);
    }
    __syncthreads();
    const int n = t >> 2, c0 = (t & 3) * 16;
    #pragma unroll
    for (int i = 0; i < 16; ++i)
        Wt[((size_t)wi * 64 + n) * CDIM + kc + c0 + i] = tile[c0 + i][n];
}

// ---------------------------------------------------------------------------
// Kernel 1: QKV projection. 64 rows of x per block, MFMA bf16.
// Wave w computes output columns [w*16, w*16+16) of each of Q, K, V.
// ---------------------------------------------------------------------------
__global__ __launch_bounds__(256) void qkv_kernel(
        const float* __restrict__ x, const short* __restrict__ Wt,
        short* __restrict__ Q, short* __restrict__ K, short* __restrict__ V) {
    __shared__ short xs[64][LPAD];
    __shared__ short wl[3][64][LPAD];
    const int t = threadIdx.x;
    const int lane = t & 63;
    const int w = t >> 6;
    const int r0 = blockIdx.x * 64;
    const int lr = lane & 15;   // row (A) / col (B,C)
    const int lg = lane >> 4;   // k-group

    f32x4 acc[3][4];
    #pragma unroll
    for (int wi = 0; wi < 3; ++wi)
        #pragma unroll
        for (int rt = 0; rt < 4; ++rt) acc[wi][rt] = f32x4{0.f, 0.f, 0.f, 0.f};

    for (int kc = 0; kc < CDIM; kc += 64) {
        __syncthreads();
        // stage x tile 64x64 fp32 -> bf16
        {
            const int r = t >> 2, c0 = (t & 3) * 16;
            const float* src = x + (size_t)(r0 + r) * CDIM + kc + c0;
            short tmp[16];
            #pragma unroll
            for (int i = 0; i < 4; ++i) {
                float4 v4 = *reinterpret_cast<const float4*>(src + i * 4);
                tmp[i*4+0] = f2bf(v4.x); tmp[i*4+1] = f2bf(v4.y);
                tmp[i*4+2] = f2bf(v4.z); tmp[i*4+3] = f2bf(v4.w);
            }
            *reinterpret_cast<short8*>(&xs[r][c0])     = *reinterpret_cast<short8*>(tmp);
            *reinterpret_cast<short8*>(&xs[r][c0 + 8]) = *reinterpret_cast<short8*>(tmp + 8);
        }
        // stage W chunks: wl[wi][n][kk] from Wt[wi][n][kc+kk] (already transposed)
        #pragma unroll
        for (int s = 0; s < 3; ++s) {
            int seg = t + 256 * s;           // 0..767
            int wi = seg >> 8, rem = seg & 255;
            int n = rem >> 2, c0 = (rem & 3) * 16;
            const short* src = Wt + ((size_t)wi * 64 + n) * CDIM + kc + c0;
            *reinterpret_cast<short8*>(&wl[wi][n][c0])     = *reinterpret_cast<const short8*>(src);
            *reinterpret_cast<short8*>(&wl[wi][n][c0 + 8]) = *reinterpret_cast<const short8*>(src + 8);
        }
        __syncthreads();

        short8 af[4][2], bf[3][2];
        #pragma unroll
        for (int rt = 0; rt < 4; ++rt)
            #pragma unroll
            for (int ks = 0; ks < 2; ++ks)
                af[rt][ks] = *reinterpret_cast<short8*>(&xs[rt*16 + lr][ks*32 + lg*8]);
        #pragma unroll
        for (int wi = 0; wi < 3; ++wi)
            #pragma unroll
            for (int ks = 0; ks < 2; ++ks)
                bf[wi][ks] = *reinterpret_cast<short8*>(&wl[wi][w*16 + lr][ks*32 + lg*8]);
        #pragma unroll
        for (int wi = 0; wi < 3; ++wi)
            #pragma unroll
            for (int rt = 0; rt < 4; ++rt)
                #pragma unroll
                for (int ks = 0; ks < 2; ++ks)
                    acc[wi][rt] = __builtin_amdgcn_mfma_f32_16x16x32_bf16(
                        af[rt][ks], bf[wi][ks], acc[wi][rt], 0, 0, 0);
    }
    // write out: C/D layout row=(lane>>4)*4+i, col=lane&15
    short* outs[3] = {Q, K, V};
    #pragma unroll
    for (int wi = 0; wi < 3; ++wi) {
        short* dst = outs[wi];
        #pragma unroll
        for (int rt = 0; rt < 4; ++rt)
            #pragma unroll
            for (int i = 0; i < 4; ++i) {
                int row = r0 + rt * 16 + lg * 4 + i;
                int col = w * 16 + lr;
                dst[(size_t)row * HDIM + col] = f2bf(acc[wi][rt][i]);
            }
    }
}

// ---------------------------------------------------------------------------
// Kernel 2: flash attention, causal. Block = 64 q-rows (4 waves x 16 rows),
// KV tile = 64. Q pre-scaled by 1/8 (folded into Wq).
// ---------------------------------------------------------------------------
__global__ __launch_bounds__(256) void attn_kernel(
        const short* __restrict__ Q, const short* __restrict__ K,
        const short* __restrict__ V, float* __restrict__ O) {
    __shared__ short Ks[64][LPAD];      // [kv][h]
    __shared__ short Vt[64][LPAD];      // [h][kv] (transposed)
    __shared__ short Ps[4][16][LPAD];   // per-wave P buffer [qrow][kv]
    const int t = threadIdx.x;
    const int lane = t & 63;
    const int w = t >> 6;
    const int qt = blockIdx.x;
    const int b = blockIdx.y;
    const int lr = lane & 15, lg = lane >> 4;

    const size_t base = (size_t)b * TLEN * HDIM;
    const int q0 = qt * 64;

    // hoist Q fragments (A-operand: row = lane&15, k = (lane>>4)*8+e)
    short8 qf[2];
    {
        const int qrow = q0 + w * 16 + lr;
        #pragma unroll
        for (int ks = 0; ks < 2; ++ks)
            qf[ks] = *reinterpret_cast<const short8*>(
                Q + base + (size_t)qrow * HDIM + ks * 32 + lg * 8);
    }

    f32x4 o_acc[4];
    #pragma unroll
    for (int h = 0; h < 4; ++h) o_acc[h] = f32x4{0.f, 0.f, 0.f, 0.f};
    float m_run[4], l_run[4];
    #pragma unroll
    for (int i = 0; i < 4; ++i) { m_run[i] = -INFINITY; l_run[i] = 0.f; }

    for (int kt = 0; kt <= qt; ++kt) {
        __syncthreads();   // guard LDS reuse
        {
            const int r = t >> 2, h0 = (t & 3) * 16;
            const short* ksrc = K + base + (size_t)(kt * 64 + r) * HDIM + h0;
            *reinterpret_cast<short8*>(&Ks[r][h0])     = *reinterpret_cast<const short8*>(ksrc);
            *reinterpret_cast<short8*>(&Ks[r][h0 + 8]) = *reinterpret_cast<const short8*>(ksrc + 8);
            const short* vsrc = V + base + (size_t)(kt * 64 + r) * HDIM + h0;
            short vtmp[16];
            *reinterpret_cast<short8*>(vtmp)     = *reinterpret_cast<const short8*>(vsrc);
            *reinterpret_cast<short8*>(vtmp + 8) = *reinterpret_cast<const short8*>(vsrc + 8);
            #pragma unroll
            for (int i = 0; i < 16; ++i) Vt[h0 + i][r] = vtmp[i];
        }
        __syncthreads();

        // S = Q K^T   (16 q-rows x 64 kv-cols per wave)
        f32x4 s[4];
        #pragma unroll
        for (int ct = 0; ct < 4; ++ct) {
            s[ct] = f32x4{0.f, 0.f, 0.f, 0.f};
            #pragma unroll
            for (int ks = 0; ks < 2; ++ks) {
                short8 kf = *reinterpret_cast<short8*>(&Ks[ct*16 + lr][ks*32 + lg*8]);
                s[ct] = __builtin_amdgcn_mfma_f32_16x16x32_bf16(qf[ks], kf, s[ct], 0, 0, 0);
            }
        }
        // causal mask on diagonal tile
        if (kt == qt) {
            #pragma unroll
            for (int ct = 0; ct < 4; ++ct) {
                int col = kt * 64 + ct * 16 + lr;
                #pragma unroll
                for (int i = 0; i < 4; ++i) {
                    int row = q0 + w * 16 + lg * 4 + i;
                    if (col > row) s[ct][i] = -1e30f;
                }
            }
        }
        // online softmax (rows lg*4+i; reduce across 16 lanes of the group)
        float p[4][4], f[4];
        #pragma unroll
        for (int i = 0; i < 4; ++i) {
            float tm = fmaxf(fmaxf(s[0][i], s[1][i]), fmaxf(s[2][i], s[3][i]));
            #pragma unroll
            for (int mb = 8; mb >= 1; mb >>= 1)
                tm = fmaxf(tm, __shfl_xor(tm, mb, 16));
            float m_new = fmaxf(m_run[i], tm);
            f[i] = __expf(m_run[i] - m_new);
            m_run[i] = m_new;
            float ls = 0.f;
            #pragma unroll
            for (int ct = 0; ct < 4; ++ct) {
                float pv = __expf(s[ct][i] - m_new);
                p[ct][i] = pv;
                ls += pv;
            }
            #pragma unroll
            for (int mb = 8; mb >= 1; mb >>= 1)
                ls += __shfl_xor(ls, mb, 16);
            l_run[i] = l_run[i] * f[i] + ls;
        }
        #pragma unroll
        for (int h = 0; h < 4; ++h)
            #pragma unroll
            for (int i = 0; i < 4; ++i)
                o_acc[h][i] *= f[i];
        // P -> per-wave LDS (layout swap: C/D -> A operand)
        #pragma unroll
        for (int ct = 0; ct < 4; ++ct)
            #pragma unroll
            for (int i = 0; i < 4; ++i)
                Ps[w][lg * 4 + i][ct * 16 + lr] = f2bf(p[ct][i]);
        // O += P V
        #pragma unroll
        for (int ks = 0; ks < 2; ++ks) {
            short8 pf = *reinterpret_cast<short8*>(&Ps[w][lr][ks*32 + lg*8]);
            #pragma unroll
            for (int h = 0; h < 4; ++h) {
                short8 vf = *reinterpret_cast<short8*>(&Vt[h*16 + lr][ks*32 + lg*8]);
                o_acc[h] = __builtin_amdgcn_mfma_f32_16x16x32_bf16(pf, vf, o_acc[h], 0, 0, 0);
            }
        }
    }
    // epilogue: normalize and store fp32
    #pragma unroll
    for (int i = 0; i < 4; ++i) {
        float inv = 1.0f / l_run[i];
        int row = q0 + w * 16 + lg * 4 + i;
        #pragma unroll
        for (int h = 0; h < 4; ++h)
            O[base + (size_t)row * HDIM + h * 16 + lr] = o_acc[h][i] * inv;
    }
}

// ---------------------------------------------------------------------------
extern "C" void kernel_launch(void* const* d_in, const int* in_sizes, int n_in,
                              void* d_out, int out_size, void* d_ws, size_t ws_size,
                              hipStream_t stream) {
    const float* x  = (const float*)d_in[0];
    const float* Wq = (const float*)d_in[1];
    const float* Wk = (const float*)d_in[2];
    const float* Wv = (const float*)d_in[3];
    float* out = (float*)d_out;

    char* ws = (char*)d_ws;
    short* Q  = (short*)(ws);
    short* K  = (short*)(ws + (size_t)2 * 1024 * 1024);
    short* V  = (short*)(ws + (size_t)4 * 1024 * 1024);
    short* Wt = (short*)(ws + (size_t)6 * 1024 * 1024);

    wt_kernel<<<dim3(16, 3), 256, 0, stream>>>(Wq, Wk, Wv, Wt);
    qkv_kernel<<<BT / 64, 256, 0, stream>>>(x, Wt, Q, K, V);
    attn_kernel<<<dim3(TLEN / 64, BATCH), 256, 0, stream>>>(Q, K, V, out);
}

// Round 4
// 156.967 us; speedup vs baseline: 1.1583x; 1.1583x over previous
//
#include <hip/hip_runtime.h>
#include <hip/hip_bf16.h>

// Problem constants
#define BATCH 8
#define TLEN 2048
#define CDIM 1024
#define HDIM 64
#define BT (BATCH * TLEN)   // 16384

typedef __attribute__((ext_vector_type(8))) short short8;
typedef __attribute__((ext_vector_type(4))) float f32x4;

#define GLOAD16(gsrc, lds) __builtin_amdgcn_global_load_lds( \
    (const __attribute__((address_space(1))) void*)(gsrc),   \
    (__attribute__((address_space(3))) void*)(lds), 16, 0, 0)

// round-to-nearest-even f32 -> bf16 (bit pattern), no HIP class round-trip
__device__ inline unsigned bfbits(float f) {
    unsigned u = __builtin_bit_cast(unsigned, f);
    return (u + 0x7fffu + ((u >> 16) & 1u)) >> 16;
}
__device__ inline short bf1(float f) { return (short)bfbits(f); }
__device__ inline unsigned pk2(float lo, float hi) {
    return bfbits(lo) | (bfbits(hi) << 16);
}

// ---------------------------------------------------------------------------
// Kernel 0: transpose + bf16-cast weights. Wt[3][64 n][1024 k] = W[k][n].
// Folds the attention scale 1/sqrt(H)=0.125 into Wq.
// ---------------------------------------------------------------------------
__global__ __launch_bounds__(256) void wt_kernel(
        const float* __restrict__ Wq, const float* __restrict__ Wk,
        const float* __restrict__ Wv, short* __restrict__ Wt) {
    const int kc = blockIdx.x * 64;
    const int wi = blockIdx.y;
    const float* W = (wi == 0) ? Wq : ((wi == 1) ? Wk : Wv);
    const float scale = (wi == 0) ? 0.125f : 1.0f;
    __shared__ short tile[64][65];
    const int t = threadIdx.x;
    #pragma unroll
    for (int i = 0; i < 16; ++i) {
        int flat = i * 256 + t;
        int kk = flat >> 6, n = flat & 63;
        tile[kk][n] = bf1(W[(size_t)(kc + kk) * HDIM + n] * scale);
    }
    __syncthreads();
    const int n = t >> 2, c0 = (t & 3) * 16;
    #pragma unroll
    for (int i = 0; i < 16; ++i)
        Wt[((size_t)wi * 64 + n) * CDIM + kc + c0 + i] = tile[c0 + i][n];
}

// ---------------------------------------------------------------------------
// Kernel 1: QKV projection. 32 rows/block (512 blocks), MFMA bf16.
// x staged fp32 + Wt staged bf16 via global_load_lds with XOR-swizzled
// SOURCE addresses (linear LDS dest, rule #21) so frag ds_read_b128 is
// conflict-light. Outputs: Q,K row-major [t][64]; V transposed Vt[b][h][t].
// ---------------------------------------------------------------------------
__global__ __launch_bounds__(256) void qkv_kernel(
        const float* __restrict__ x, const short* __restrict__ Wt,
        short* __restrict__ Q, short* __restrict__ K, short* __restrict__ Vt) {
    __shared__ float xs[32 * 64];      // 8 KB, swizzled
    __shared__ short wl[3 * 64 * 64];  // 24 KB, swizzled
    __shared__ short ob[32 * 72];      // 4.5 KB epilogue staging (padded)
    const int t = threadIdx.x;
    const int lane = t & 63, w = t >> 6;
    const int lr = lane & 15, lg = lane >> 4;
    const int r0 = blockIdx.x * 32;

    f32x4 acc[3][2];
    #pragma unroll
    for (int wi = 0; wi < 3; ++wi)
        #pragma unroll
        for (int rt = 0; rt < 2; ++rt) acc[wi][rt] = f32x4{0.f, 0.f, 0.f, 0.f};

    for (int kc = 0; kc < CDIM; kc += 64) {
        __syncthreads();
        // stage x tile 32x64 fp32: 16B chunks, source pre-swizzled
        #pragma unroll
        for (int i = 0; i < 2; ++i) {
            int chunk = t + 256 * i;
            int row = chunk >> 4, slot = chunk & 15;
            GLOAD16(x + (size_t)(r0 + row) * CDIM + kc + ((slot ^ (row & 7)) << 2),
                    xs + chunk * 4);
        }
        // stage Wt chunk [3][64][64] bf16
        #pragma unroll
        for (int i = 0; i < 6; ++i) {
            int chunk = t + 256 * i;
            int R = chunk >> 3, slot = chunk & 7;
            GLOAD16(Wt + (size_t)R * CDIM + kc + ((slot ^ (R & 7)) << 3),
                    wl + chunk * 8);
        }
        __syncthreads();

        short8 af[2][2];
        #pragma unroll
        for (int rt = 0; rt < 2; ++rt)
            #pragma unroll
            for (int ks = 0; ks < 2; ++ks) {
                int row = rt * 16 + lr;
                int s0 = ks * 8 + lg * 2;
                f32x4 a0 = *(const f32x4*)(xs + row * 64 + (((s0)     ^ (row & 7)) << 2));
                f32x4 a1 = *(const f32x4*)(xs + row * 64 + (((s0 + 1) ^ (row & 7)) << 2));
                uint4 uu;
                uu.x = pk2(a0[0], a0[1]); uu.y = pk2(a0[2], a0[3]);
                uu.z = pk2(a1[0], a1[1]); uu.w = pk2(a1[2], a1[3]);
                af[rt][ks] = __builtin_bit_cast(short8, uu);
            }
        #pragma unroll
        for (int wi = 0; wi < 3; ++wi)
            #pragma unroll
            for (int ks = 0; ks < 2; ++ks) {
                int R = wi * 64 + w * 16 + lr;
                short8 bf = *(const short8*)(wl + R * 64 + (((ks * 4 + lg) ^ (lr & 7)) << 3));
                #pragma unroll
                for (int rt = 0; rt < 2; ++rt)
                    acc[wi][rt] = __builtin_amdgcn_mfma_f32_16x16x32_bf16(
                        af[rt][ks], bf, acc[wi][rt], 0, 0, 0);
            }
    }
    // V epilogue: C/D rows are consecutive t -> pack pairs, 8B stores to Vt[b][h][t]
    {
        const int bb = r0 >> 11, t0 = r0 & 2047;
        #pragma unroll
        for (int rt = 0; rt < 2; ++rt) {
            uint2 uv;
            uv.x = pk2(acc[2][rt][0], acc[2][rt][1]);
            uv.y = pk2(acc[2][rt][2], acc[2][rt][3]);
            *(uint2*)(Vt + ((size_t)bb * HDIM + w * 16 + lr) * TLEN + t0 + rt * 16 + lg * 4) = uv;
        }
    }
    // Q, K epilogue via LDS transpose -> coalesced short8 stores
    #pragma unroll
    for (int wi = 0; wi < 2; ++wi) {
        __syncthreads();
        #pragma unroll
        for (int rt = 0; rt < 2; ++rt)
            #pragma unroll
            for (int i = 0; i < 4; ++i)
                ob[(rt * 16 + lg * 4 + i) * 72 + w * 16 + lr] = bf1(acc[wi][rt][i]);
        __syncthreads();
        int row = t >> 3, c0 = (t & 7) * 8;
        short8 v = *(short8*)(ob + row * 72 + c0);
        short* dst = (wi == 0) ? Q : K;
        *(short8*)(dst + (size_t)(r0 + row) * HDIM + c0) = v;
    }
}

// ---------------------------------------------------------------------------
// Kernel 2: flash attention, causal, swapped QK^T (S^T = mfma(K, Q)).
// One 16-row q-tile per block; ALL 4 waves split its kv supertiles 4-way
// (s = w, w+4, ...) with no barriers in the loop; the 4 partial (m,l,O^T)
// states merge once via LDS at the end. qi = 127 - blockIdx.y dispatches
// heavy tiles first so light ones backfill the tail.
// Per-lane state is for q-row = lane&15: softmax in-lane + 2 shfl_xor;
// O accumulated as O^T (mfma(Vt, P)) so rescale/normalize are in-lane.
// ---------------------------------------------------------------------------
__global__ __launch_bounds__(256) void attn_kernel(
        const short* __restrict__ Q, const short* __restrict__ K,
        const short* __restrict__ Vt, float* __restrict__ O) {
    __shared__ short Ps[4][16 * 64];   // per-wave P buffer, XOR-swizzled (8 KB)
    __shared__ float Om[4][16 * 68];   // per-wave [q][h] partials, padded (17 KB)
    __shared__ float ml[4][2][16];     // per-wave {m,l}[q]
    const int t = threadIdx.x, lane = t & 63, w = t >> 6;
    const int lr = lane & 15, lg = lane >> 4;
    const int b = blockIdx.x;
    const int qi = (TLEN / 16 - 1) - blockIdx.y;   // descending: heavy first
    const int q0 = qi * 16;
    const size_t base = (size_t)b * TLEN * HDIM;
    const short* Kb = K + base;
    const short* Vb = Vt + base;    // same per-batch stride (64*2048)

    // Q B-operand fragments: col = q = lr, k = h = ks*32 + lg*8 + e
    short8 qf0 = *(const short8*)(Q + base + (size_t)(q0 + lr) * HDIM + lg * 8);
    short8 qf1 = *(const short8*)(Q + base + (size_t)(q0 + lr) * HDIM + 32 + lg * 8);

    f32x4 o[4];
    #pragma unroll
    for (int ht = 0; ht < 4; ++ht) o[ht] = f32x4{0.f, 0.f, 0.f, 0.f};
    float m = -1e30f, l = 0.f;

    char* myPs = (char*)Ps[w];
    const int swz = (lr & 7) << 4;           // byte XOR within 128B row
    const int nsup = (q0 + 79) >> 6;         // supertiles of 64 kv

    for (int s = w; s < nsup; s += 4) {
        const int kv0 = s * 64;
        f32x4 st[2][2];
        // S^T = K Q^T : rows = kv, cols = q
        #pragma unroll
        for (int h2 = 0; h2 < 2; ++h2)
            #pragma unroll
            for (int kt = 0; kt < 2; ++kt) {
                const short* kp = Kb + (size_t)(kv0 + h2 * 32 + kt * 16 + lr) * HDIM + lg * 8;
                short8 k0 = *(const short8*)kp;
                short8 k1 = *(const short8*)(kp + 32);
                f32x4 a = f32x4{0.f, 0.f, 0.f, 0.f};
                a = __builtin_amdgcn_mfma_f32_16x16x32_bf16(k0, qf0, a, 0, 0, 0);
                a = __builtin_amdgcn_mfma_f32_16x16x32_bf16(k1, qf1, a, 0, 0, 0);
                st[h2][kt] = a;
            }
        if (s == nsup - 1) {              // diagonal supertile: mask kv > q
            const int q = q0 + lr;
            #pragma unroll
            for (int h2 = 0; h2 < 2; ++h2)
                #pragma unroll
                for (int kt = 0; kt < 2; ++kt)
                    #pragma unroll
                    for (int i = 0; i < 4; ++i)
                        if (kv0 + h2 * 32 + kt * 16 + lg * 4 + i > q)
                            st[h2][kt][i] = -1e30f;
        }
        // online softmax for q-row lr: in-lane over 16 vals + 2 shfl
        float tm = -1e30f;
        #pragma unroll
        for (int h2 = 0; h2 < 2; ++h2)
            #pragma unroll
            for (int kt = 0; kt < 2; ++kt)
                #pragma unroll
                for (int i = 0; i < 4; ++i) tm = fmaxf(tm, st[h2][kt][i]);
        tm = fmaxf(tm, __shfl_xor(tm, 16));
        tm = fmaxf(tm, __shfl_xor(tm, 32));
        float mn = fmaxf(m, tm);
        float fs = __expf(m - mn);
        m = mn;
        float ls = 0.f;
        #pragma unroll
        for (int h2 = 0; h2 < 2; ++h2)
            #pragma unroll
            for (int kt = 0; kt < 2; ++kt)
                #pragma unroll
                for (int i = 0; i < 4; ++i) {
                    float e = __expf(st[h2][kt][i] - mn);
                    st[h2][kt][i] = e;
                    ls += e;
                }
        ls += __shfl_xor(ls, 16);
        ls += __shfl_xor(ls, 32);
        l = l * fs + ls;
        #pragma unroll
        for (int ht = 0; ht < 4; ++ht)
            #pragma unroll
            for (int i = 0; i < 4; ++i) o[ht][i] *= fs;
        // pack P -> per-wave swizzled LDS (row = q = lr), then B-frag reads
        #pragma unroll
        for (int h2 = 0; h2 < 2; ++h2)
            #pragma unroll
            for (int kt = 0; kt < 2; ++kt) {
                unsigned u0 = pk2(st[h2][kt][0], st[h2][kt][1]);
                unsigned u1 = pk2(st[h2][kt][2], st[h2][kt][3]);
                int byt = lr * 128 + (((h2 * 64 + kt * 32 + lg * 8)) ^ swz);
                *(unsigned*)(myPs + byt) = u0;
                *(unsigned*)(myPs + byt + 4) = u1;
            }
        short8 pb0 = *(short8*)(myPs + lr * 128 + ((lg * 16) ^ swz));
        short8 pb1 = *(short8*)(myPs + lr * 128 + ((64 + lg * 16) ^ swz));
        // O^T += V^T P : A = Vt rows (h), B = P (col=q, k=kv)
        #pragma unroll
        for (int h2 = 0; h2 < 2; ++h2) {
            short8 pb = h2 ? pb1 : pb0;
            #pragma unroll
            for (int ht = 0; ht < 4; ++ht) {
                const short* vp = Vb + (size_t)(ht * 16 + lr) * TLEN + kv0 + h2 * 32 + lg * 8;
                short8 vf = *(const short8*)vp;
                o[ht] = __builtin_amdgcn_mfma_f32_16x16x32_bf16(vf, pb, o[ht], 0, 0, 0);
            }
        }
    }
    // write partial state (transpose O^T -> [q][h] in LDS)
    {
        float* om = Om[w];
        #pragma unroll
        for (int ht = 0; ht < 4; ++ht)
            *(f32x4*)(om + lr * 68 + ht * 16 + lg * 4) = o[ht];
        if (lg == 0) {
            ml[w][0][lr] = m;
            ml[w][1][lr] = l;
        }
    }
    __syncthreads();
    // merge 4 partials: thread (w,lane) handles q = lr, h = w*16 + lg*4 .. +3
    {
        float mp[4], fp[4];
        float mm = -1e30f;
        #pragma unroll
        for (int p = 0; p < 4; ++p) { mp[p] = ml[p][0][lr]; mm = fmaxf(mm, mp[p]); }
        float lsum = 0.f;
        #pragma unroll
        for (int p = 0; p < 4; ++p) {
            fp[p] = __expf(mp[p] - mm);
            lsum += ml[p][1][lr] * fp[p];
        }
        float inv = 1.0f / lsum;
        const int off = lr * 68 + w * 16 + lg * 4;
        f32x4 r = f32x4{0.f, 0.f, 0.f, 0.f};
        #pragma unroll
        for (int p = 0; p < 4; ++p) {
            f32x4 v = *(const f32x4*)(&Om[p][off]);
            #pragma unroll
            for (int i = 0; i < 4; ++i) r[i] += v[i] * fp[p];
        }
        #pragma unroll
        for (int i = 0; i < 4; ++i) r[i] *= inv;
        *(f32x4*)(O + base + (size_t)(q0 + lr) * HDIM + w * 16 + lg * 4) = r;
    }
}

// ---------------------------------------------------------------------------
extern "C" void kernel_launch(void* const* d_in, const int* in_sizes, int n_in,
                              void* d_out, int out_size, void* d_ws, size_t ws_size,
                              hipStream_t stream) {
    const float* x  = (const float*)d_in[0];
    const float* Wq = (const float*)d_in[1];
    const float* Wk = (const float*)d_in[2];
    const float* Wv = (const float*)d_in[3];
    float* out = (float*)d_out;

    char* ws = (char*)d_ws;
    short* Q  = (short*)(ws);
    short* K  = (short*)(ws + (size_t)2 * 1024 * 1024);
    short* Vt = (short*)(ws + (size_t)4 * 1024 * 1024);
    short* Wt = (short*)(ws + (size_t)6 * 1024 * 1024);

    wt_kernel<<<dim3(16, 3), 256, 0, stream>>>(Wq, Wk, Wv, Wt);
    qkv_kernel<<<BT / 32, 256, 0, stream>>>(x, Wt, Q, K, Vt);
    attn_kernel<<<dim3(BATCH, TLEN / 16), 256, 0, stream>>>(Q, K, Vt, out);
}

// Round 5
// 146.123 us; speedup vs baseline: 1.2443x; 1.0742x over previous
//
#include <hip/hip_runtime.h>
#include <hip/hip_bf16.h>

// Problem constants
#define BATCH 8
#define TLEN 2048
#define CDIM 1024
#define HDIM 64
#define BT (BATCH * TLEN)   // 16384

typedef __attribute__((ext_vector_type(8))) short short8;
typedef __attribute__((ext_vector_type(4))) float f32x4;

#define GLOAD16(gsrc, lds) __builtin_amdgcn_global_load_lds( \
    (const __attribute__((address_space(1))) void*)(gsrc),   \
    (__attribute__((address_space(3))) void*)(lds), 16, 0, 0)

// round-to-nearest-even f32 -> bf16 (bit pattern)
__device__ inline unsigned bfbits(float f) {
    unsigned u = __builtin_bit_cast(unsigned, f);
    return (u + 0x7fffu + ((u >> 16) & 1u)) >> 16;
}
__device__ inline short bf1(float f) { return (short)bfbits(f); }
// packed f32x2 -> bf16x2 via HW instruction (src0 -> low half)
__device__ inline unsigned cvtpk(float lo, float hi) {
    unsigned r;
    asm("v_cvt_pk_bf16_f32 %0, %1, %2" : "=v"(r) : "v"(lo), "v"(hi));
    return r;
}

// ---------------------------------------------------------------------------
// Kernel 0: transpose + bf16-cast weights. Wt[3][64 n][1024 k] = W[k][n].
// Folds the attention scale 1/sqrt(H)=0.125 into Wq.
// ---------------------------------------------------------------------------
__global__ __launch_bounds__(256) void wt_kernel(
        const float* __restrict__ Wq, const float* __restrict__ Wk,
        const float* __restrict__ Wv, short* __restrict__ Wt) {
    const int kc = blockIdx.x * 64;
    const int wi = blockIdx.y;
    const float* W = (wi == 0) ? Wq : ((wi == 1) ? Wk : Wv);
    const float scale = (wi == 0) ? 0.125f : 1.0f;
    __shared__ short tile[64][65];
    const int t = threadIdx.x;
    #pragma unroll
    for (int i = 0; i < 16; ++i) {
        int flat = i * 256 + t;
        int kk = flat >> 6, n = flat & 63;
        tile[kk][n] = bf1(W[(size_t)(kc + kk) * HDIM + n] * scale);
    }
    __syncthreads();
    const int n = t >> 2, c0 = (t & 3) * 16;
    #pragma unroll
    for (int i = 0; i < 16; ++i)
        Wt[((size_t)wi * 64 + n) * CDIM + kc + c0 + i] = tile[c0 + i][n];
}

// ---------------------------------------------------------------------------
// Kernel 1: QKV projection, 32 rows/block (512 blocks), 2-phase pipelined:
// double-buffered LDS, stage(next) issued BEFORE compute(cur), one barrier
// per K-step so global_load_lds latency hides under MFMA + cvt_pk.
// Outputs: Q,K row-major [t][64]; V transposed Vt[b][h][t].
// ---------------------------------------------------------------------------
__global__ __launch_bounds__(256) void qkv_kernel(
        const float* __restrict__ x, const short* __restrict__ Wt,
        short* __restrict__ Q, short* __restrict__ K, short* __restrict__ Vt) {
    __shared__ float xs[2][32 * 64];      // 2 x 8 KB, swizzled
    __shared__ short wl[2][3 * 64 * 64];  // 2 x 24 KB, swizzled
    __shared__ short ob[32 * 72];         // epilogue staging (padded)
    const int t = threadIdx.x;
    const int lane = t & 63, w = t >> 6;
    const int lr = lane & 15, lg = lane >> 4;
    const int r0 = blockIdx.x * 32;

    auto stage = [&](int buf, int kc) {
        #pragma unroll
        for (int i = 0; i < 2; ++i) {
            int chunk = t + 256 * i;
            int row = chunk >> 4, slot = chunk & 15;
            GLOAD16(x + (size_t)(r0 + row) * CDIM + kc + ((slot ^ (row & 7)) << 2),
                    xs[buf] + chunk * 4);
        }
        #pragma unroll
        for (int i = 0; i < 6; ++i) {
            int chunk = t + 256 * i;
            int R = chunk >> 3, slot = chunk & 7;
            GLOAD16(Wt + (size_t)R * CDIM + kc + ((slot ^ (R & 7)) << 3),
                    wl[buf] + chunk * 8);
        }
    };

    f32x4 acc[3][2];
    #pragma unroll
    for (int wi = 0; wi < 3; ++wi)
        #pragma unroll
        for (int rt = 0; rt < 2; ++rt) acc[wi][rt] = f32x4{0.f, 0.f, 0.f, 0.f};

    stage(0, 0);
    int cur = 0;
    for (int kc = 0; kc < CDIM; kc += 64) {
        __syncthreads();                       // drains prior stage (vmcnt(0))
        if (kc + 64 < CDIM) stage(cur ^ 1, kc + 64);   // in flight during compute
        const float* xsc = xs[cur];
        const short* wlc = wl[cur];

        short8 af[2][2];
        #pragma unroll
        for (int rt = 0; rt < 2; ++rt)
            #pragma unroll
            for (int ks = 0; ks < 2; ++ks) {
                int row = rt * 16 + lr;
                int s0 = ks * 8 + lg * 2;
                f32x4 a0 = *(const f32x4*)(xsc + row * 64 + (((s0)     ^ (row & 7)) << 2));
                f32x4 a1 = *(const f32x4*)(xsc + row * 64 + (((s0 + 1) ^ (row & 7)) << 2));
                uint4 uu;
                uu.x = cvtpk(a0[0], a0[1]); uu.y = cvtpk(a0[2], a0[3]);
                uu.z = cvtpk(a1[0], a1[1]); uu.w = cvtpk(a1[2], a1[3]);
                af[rt][ks] = __builtin_bit_cast(short8, uu);
            }
        #pragma unroll
        for (int wi = 0; wi < 3; ++wi)
            #pragma unroll
            for (int ks = 0; ks < 2; ++ks) {
                int R = wi * 64 + w * 16 + lr;
                short8 bfv = *(const short8*)(wlc + R * 64 + (((ks * 4 + lg) ^ (lr & 7)) << 3));
                #pragma unroll
                for (int rt = 0; rt < 2; ++rt)
                    acc[wi][rt] = __builtin_amdgcn_mfma_f32_16x16x32_bf16(
                        af[rt][ks], bfv, acc[wi][rt], 0, 0, 0);
            }
        cur ^= 1;
    }
    // V epilogue: C/D rows are consecutive t -> pack pairs, 8B stores to Vt[b][h][t]
    {
        const int bb = r0 >> 11, t0 = r0 & 2047;
        #pragma unroll
        for (int rt = 0; rt < 2; ++rt) {
            uint2 uv;
            uv.x = cvtpk(acc[2][rt][0], acc[2][rt][1]);
            uv.y = cvtpk(acc[2][rt][2], acc[2][rt][3]);
            *(uint2*)(Vt + ((size_t)bb * HDIM + w * 16 + lr) * TLEN + t0 + rt * 16 + lg * 4) = uv;
        }
    }
    // Q, K epilogue via LDS transpose -> coalesced short8 stores
    #pragma unroll
    for (int wi = 0; wi < 2; ++wi) {
        __syncthreads();
        #pragma unroll
        for (int rt = 0; rt < 2; ++rt)
            #pragma unroll
            for (int i = 0; i < 4; ++i)
                ob[(rt * 16 + lg * 4 + i) * 72 + w * 16 + lr] = bf1(acc[wi][rt][i]);
        __syncthreads();
        int row = t >> 3, c0 = (t & 7) * 8;
        short8 v = *(short8*)(ob + row * 72 + c0);
        short* dst = (wi == 0) ? Q : K;
        *(short8*)(dst + (size_t)(r0 + row) * HDIM + c0) = v;
    }
}

// ---------------------------------------------------------------------------
// Kernel 2: flash attention, causal, swapped QK^T (S^T = mfma(K, Q)).
// Each block processes TWO q-tiles (127-y, then y) so total work per block
// is ~constant. All 4 waves split a tile's kv supertiles 4-way (s=w, w+4...)
// with no barriers in the loop; 4 partial (m,l,O^T) states merge via LDS.
// K is register-double-buffered one supertile ahead; V loads issue at the
// top of compute so global latency hides under QK MFMA + softmax + P pack.
// ---------------------------------------------------------------------------
__global__ __launch_bounds__(256, 2) void attn_kernel(
        const short* __restrict__ Q, const short* __restrict__ K,
        const short* __restrict__ Vt, float* __restrict__ O) {
    __shared__ short Ps[4][16 * 64];   // per-wave P buffer, XOR-swizzled
    __shared__ float Om[4][16 * 68];   // per-wave [q][h] partials, padded
    __shared__ float ml[4][2][16];     // per-wave {m,l}[q]
    const int t = threadIdx.x, lane = t & 63, w = t >> 6;
    const int lr = lane & 15, lg = lane >> 4;
    const int b = blockIdx.x;
    const size_t base = (size_t)b * TLEN * HDIM;
    const short* Kb = K + base;
    const short* Vb = Vt + base;    // same per-batch stride (64*2048)
    char* myPs = (char*)Ps[w];
    const int swz = (lr & 7) << 4;  // byte XOR within 128B row

    auto run_tile = [&](int qi) {
        const int q0 = qi * 16;
        const int nsup = (q0 + 79) >> 6;   // supertiles of 64 kv
        // Q B-operand fragments: col = q = lr, k = h
        short8 qf0 = *(const short8*)(Q + base + (size_t)(q0 + lr) * HDIM + lg * 8);
        short8 qf1 = *(const short8*)(Q + base + (size_t)(q0 + lr) * HDIM + 32 + lg * 8);

        f32x4 o[4];
        #pragma unroll
        for (int ht = 0; ht < 4; ++ht) o[ht] = f32x4{0.f, 0.f, 0.f, 0.f};
        float m = -1e30f, l = 0.f;

        auto loadK = [&](int s, short8* kf) {
            const int kv0 = s * 64;
            #pragma unroll
            for (int h2 = 0; h2 < 2; ++h2)
                #pragma unroll
                for (int kt = 0; kt < 2; ++kt) {
                    const short* kp = Kb + (size_t)(kv0 + h2 * 32 + kt * 16 + lr) * HDIM + lg * 8;
                    kf[(h2 * 2 + kt) * 2]     = *(const short8*)kp;
                    kf[(h2 * 2 + kt) * 2 + 1] = *(const short8*)(kp + 32);
                }
        };
        auto compute = [&](int s, const short8* kf) {
            const int kv0 = s * 64;
            // issue V loads first: latency hides under QK + softmax + P pack
            short8 vf[8];
            #pragma unroll
            for (int h2 = 0; h2 < 2; ++h2)
                #pragma unroll
                for (int ht = 0; ht < 4; ++ht)
                    vf[h2 * 4 + ht] = *(const short8*)(
                        Vb + (size_t)(ht * 16 + lr) * TLEN + kv0 + h2 * 32 + lg * 8);
            // S^T = K Q^T : rows = kv, cols = q
            f32x4 st[2][2];
            #pragma unroll
            for (int h2 = 0; h2 < 2; ++h2)
                #pragma unroll
                for (int kt = 0; kt < 2; ++kt) {
                    f32x4 a = f32x4{0.f, 0.f, 0.f, 0.f};
                    a = __builtin_amdgcn_mfma_f32_16x16x32_bf16(kf[(h2*2+kt)*2],     qf0, a, 0, 0, 0);
                    a = __builtin_amdgcn_mfma_f32_16x16x32_bf16(kf[(h2*2+kt)*2 + 1], qf1, a, 0, 0, 0);
                    st[h2][kt] = a;
                }
            if (s == nsup - 1) {              // diagonal supertile: mask kv > q
                const int q = q0 + lr;
                #pragma unroll
                for (int h2 = 0; h2 < 2; ++h2)
                    #pragma unroll
                    for (int kt = 0; kt < 2; ++kt)
                        #pragma unroll
                        for (int i = 0; i < 4; ++i)
                            if (kv0 + h2 * 32 + kt * 16 + lg * 4 + i > q)
                                st[h2][kt][i] = -1e30f;
            }
            // online softmax for q-row lr: in-lane over 16 vals + 2 shfl
            float tm = -1e30f;
            #pragma unroll
            for (int h2 = 0; h2 < 2; ++h2)
                #pragma unroll
                for (int kt = 0; kt < 2; ++kt)
                    #pragma unroll
                    for (int i = 0; i < 4; ++i) tm = fmaxf(tm, st[h2][kt][i]);
            tm = fmaxf(tm, __shfl_xor(tm, 16));
            tm = fmaxf(tm, __shfl_xor(tm, 32));
            float mn = fmaxf(m, tm);
            float fs = __expf(m - mn);
            m = mn;
            float ls = 0.f;
            #pragma unroll
            for (int h2 = 0; h2 < 2; ++h2)
                #pragma unroll
                for (int kt = 0; kt < 2; ++kt)
                    #pragma unroll
                    for (int i = 0; i < 4; ++i) {
                        float e = __expf(st[h2][kt][i] - mn);
                        st[h2][kt][i] = e;
                        ls += e;
                    }
            ls += __shfl_xor(ls, 16);
            ls += __shfl_xor(ls, 32);
            l = l * fs + ls;
            #pragma unroll
            for (int ht = 0; ht < 4; ++ht)
                #pragma unroll
                for (int i = 0; i < 4; ++i) o[ht][i] *= fs;
            // pack P -> per-wave swizzled LDS (row = q = lr), then B-frag reads
            #pragma unroll
            for (int h2 = 0; h2 < 2; ++h2)
                #pragma unroll
                for (int kt = 0; kt < 2; ++kt) {
                    uint2 u;
                    u.x = cvtpk(st[h2][kt][0], st[h2][kt][1]);
                    u.y = cvtpk(st[h2][kt][2], st[h2][kt][3]);
                    *(uint2*)(myPs + lr * 128 + ((h2 * 64 + kt * 32 + lg * 8) ^ swz)) = u;
                }
            short8 pb0 = *(short8*)(myPs + lr * 128 + ((lg * 16) ^ swz));
            short8 pb1 = *(short8*)(myPs + lr * 128 + ((64 + lg * 16) ^ swz));
            // O^T += V^T P
            #pragma unroll
            for (int h2 = 0; h2 < 2; ++h2) {
                short8 pb = h2 ? pb1 : pb0;
                #pragma unroll
                for (int ht = 0; ht < 4; ++ht)
                    o[ht] = __builtin_amdgcn_mfma_f32_16x16x32_bf16(
                        vf[h2 * 4 + ht], pb, o[ht], 0, 0, 0);
            }
        };

        // software-pipelined loop: K prefetched one supertile ahead
        short8 ka[8], kb2[8];
        int s = w;
        if (s < nsup) loadK(s, ka);
        while (s < nsup) {
            if (s + 4 < nsup) loadK(s + 4, kb2);
            compute(s, ka);
            s += 4;
            if (s >= nsup) break;
            if (s + 4 < nsup) loadK(s + 4, ka);
            compute(s, kb2);
            s += 4;
        }
        // write partial state
        {
            float* om = Om[w];
            #pragma unroll
            for (int ht = 0; ht < 4; ++ht)
                *(f32x4*)(om + lr * 68 + ht * 16 + lg * 4) = o[ht];
            if (lg == 0) {
                ml[w][0][lr] = m;
                ml[w][1][lr] = l;
            }
        }
        __syncthreads();
        // merge 4 partials: thread (w,lane) handles q = lr, h = w*16 + lg*4 ..
        {
            float mp[4], fp[4];
            float mm = -1e30f;
            #pragma unroll
            for (int p = 0; p < 4; ++p) { mp[p] = ml[p][0][lr]; mm = fmaxf(mm, mp[p]); }
            float lsum = 0.f;
            #pragma unroll
            for (int p = 0; p < 4; ++p) {
                fp[p] = __expf(mp[p] - mm);
                lsum += ml[p][1][lr] * fp[p];
            }
            float inv = 1.0f / lsum;
            const int off = lr * 68 + w * 16 + lg * 4;
            f32x4 r = f32x4{0.f, 0.f, 0.f, 0.f};
            #pragma unroll
            for (int p = 0; p < 4; ++p) {
                f32x4 v = *(const f32x4*)(&Om[p][off]);
                #pragma unroll
                for (int i = 0; i < 4; ++i) r[i] += v[i] * fp[p];
            }
            #pragma unroll
            for (int i = 0; i < 4; ++i) r[i] *= inv;
            *(f32x4*)(O + base + (size_t)(q0 + lr) * HDIM + w * 16 + lg * 4) = r;
        }
    };

    run_tile((TLEN / 16 - 1) - blockIdx.y);   // heavy tile
    __syncthreads();                          // Om/ml reuse guard
    run_tile(blockIdx.y);                     // complementary light tile
}

// ---------------------------------------------------------------------------
extern "C" void kernel_launch(void* const* d_in, const int* in_sizes, int n_in,
                              void* d_out, int out_size, void* d_ws, size_t ws_size,
                              hipStream_t stream) {
    const float* x  = (const float*)d_in[0];
    const float* Wq = (const float*)d_in[1];
    const float* Wk = (const float*)d_in[2];
    const float* Wv = (const float*)d_in[3];
    float* out = (float*)d_out;

    char* ws = (char*)d_ws;
    short* Q  = (short*)(ws);
    short* K  = (short*)(ws + (size_t)2 * 1024 * 1024);
    short* Vt = (short*)(ws + (size_t)4 * 1024 * 1024);
    short* Wt = (short*)(ws + (size_t)6 * 1024 * 1024);

    wt_kernel<<<dim3(16, 3), 256, 0, stream>>>(Wq, Wk, Wv, Wt);
    qkv_kernel<<<BT / 32, 256, 0, stream>>>(x, Wt, Q, K, Vt);
    attn_kernel<<<dim3(BATCH, TLEN / 32), 256, 0, stream>>>(Q, K, Vt, out);
}